// Round 19
// baseline (297.627 us; speedup 1.0000x reference)
//
#include <hip/hip_runtime.h>
#include <hip/hip_bf16.h>
#include <math.h>

// Problem constants
#define B_ 2
#define T_ 2048
#define C_ 2048
#define H_ 16
#define HD_ 128
#define LORA_ 512
#define RD_ 64
#define ND_ 64
#define BT_ (B_*T_)            // 4096
#define NKVA_ 576              // LORA + RD
#define NKVAP_ 640             // padded to 128
#define LOG2_THETA 16.609640474436812f

typedef __bf16 bf16x8 __attribute__((ext_vector_type(8)));
typedef float  f32x4  __attribute__((ext_vector_type(4)));

#define MFMA16(a,b,c) __builtin_amdgcn_mfma_f32_16x16x32_bf16((a),(b),(c),0,0,0)

// global -> LDS direct 16B copy (lds dest must be wave-uniform base + lane*16)
__device__ static inline void load_lds16(const __bf16* g, __bf16* l) {
  auto* lp = (__attribute__((address_space(3))) char*)(uintptr_t)(l);
  auto* gp = (const __attribute__((address_space(1))) char*)(g);
  __builtin_amdgcn_global_load_lds(gp, lp, 16, 0, 0);
}

__device__ static inline unsigned pkbf(float a, float b) {
  union { __bf16 h[2]; unsigned u; } v;
  v.h[0] = (__bf16)a; v.h[1] = (__bf16)b;
  return v.u;
}

// ---------------------------------------------------------------- fused prologue
// R14-verified: cast_x + 4 weight transposes, one dispatch.
// Partition: 4096 (cast_x) + 4096 (Wq) + 1280 (Wkva) + 512 (Wkvb) + 2048 (Wo)
__global__ __launch_bounds__(256) void k_prep(const float* __restrict__ x,
                                              const float* __restrict__ Wq,
                                              const float* __restrict__ Wkva,
                                              const float* __restrict__ Wkvb,
                                              const float* __restrict__ Wo,
                                              __bf16* __restrict__ xb,
                                              __bf16* __restrict__ WqT,
                                              __bf16* __restrict__ WkvaT,
                                              __bf16* __restrict__ WkvbT,
                                              __bf16* __restrict__ WoTc) {
  __shared__ float tile[32][33];
  const int id = blockIdx.x;
  const int tid = threadIdx.x;
  if (id < 4096) {
    // cast_x, 8 elems/thread over BT_*C_ = 8388608
    const int idx = id * 256 + tid;
    const float* xp = x + (size_t)idx * 8;
    float4 a = *(const float4*)xp, bb = *(const float4*)(xp + 4);
    union { __bf16 h[8]; bf16x8 v; } o;
    o.h[0] = (__bf16)a.x;  o.h[1] = (__bf16)a.y;
    o.h[2] = (__bf16)a.z;  o.h[3] = (__bf16)a.w;
    o.h[4] = (__bf16)bb.x; o.h[5] = (__bf16)bb.y;
    o.h[6] = (__bf16)bb.z; o.h[7] = (__bf16)bb.w;
    *(bf16x8*)(xb + (size_t)idx * 8) = o.v;
    return;
  }
  const int tx = tid & 31, ty = tid >> 5;
  if (id < 9984) {
    // k_tcast: dst[n][k] = src[k][n], zero-fill n in [N,NP)
    const float* src; __bf16* dst; int K, N, bx, by;
    if (id < 8192)      { src = Wq;   dst = WqT;   K = 2048; N = 2048; int l = id - 4096; bx = l & 63; by = l >> 6; }
    else if (id < 9472) { src = Wkva; dst = WkvaT; K = 2048; N = NKVA_; int l = id - 8192; bx = l & 63; by = l >> 6; }
    else                { src = Wkvb; dst = WkvbT; K = 512;  N = 1024; int l = id - 9472; bx = l & 15; by = l >> 4; }
    const int k0 = bx * 32, n0 = by * 32;
    for (int i = ty; i < 32; i += 8) {
      int n = n0 + tx;
      tile[i][tx] = (n < N) ? src[(size_t)(k0 + i) * N + n] : 0.0f;
    }
    __syncthreads();
    for (int i = ty; i < 32; i += 8)
      dst[(size_t)(n0 + i) * K + k0 + tx] = (__bf16)tile[tx][i];
    return;
  }
  {
    // k_tcast_wo: dst[n][kc] = Wo[(kc>>6)*128 + (kc&63)][n]
    const int l = id - 9984;
    const int kc0 = (l & 31) * 32;
    const int n0  = (l >> 5) * 32;
    const int rbase = (kc0 >> 6) * 128 + (kc0 & 63);
    for (int i = ty; i < 32; i += 8)
      tile[i][tx] = Wo[(size_t)(rbase + i) * C_ + n0 + tx];
    __syncthreads();
    for (int i = ty; i < 32; i += 8)
      WoTc[(size_t)(n0 + i) * 1024 + kc0 + tx] = (__bf16)tile[tx][i];
  }
}

// ---------------------------------------------------------------- GEMM
// R8-verified: 128x128 tile, BK=32, 4 waves, 256 threads, double-buffered
// global_load_lds staging. Used for Wkvb and Wo.
__global__ __launch_bounds__(256) void k_gemm_bt(const __bf16* __restrict__ A,
                                                 const __bf16* __restrict__ B,
                                                 float* __restrict__ C,
                                                 int M, int N, int K) {
  __shared__ __align__(16) __bf16 As[2][128 * 32];
  __shared__ __align__(16) __bf16 Bs[2][128 * 32];
  const int tid  = threadIdx.x;
  const int lane = tid & 63;
  const int wave = tid >> 6;
  const int bm = blockIdx.x, bn = blockIdx.y;
  const int r0 = tid >> 2;
  const int c8 = (tid & 3) * 8;
  const __bf16* Ag = A + (size_t)(bm * 128 + r0) * K + c8;
  const __bf16* Bg = B + (size_t)(bn * 128 + r0) * K + c8;
  const int wr = (wave >> 1) * 64, wc = (wave & 1) * 64;
  const int fr = lane & 15, fk = (lane >> 4) * 8;
  const f32x4 fzero = {0.f, 0.f, 0.f, 0.f};
  f32x4 acc[4][4];
#pragma unroll
  for (int i = 0; i < 4; ++i)
#pragma unroll
    for (int j = 0; j < 4; ++j) acc[i][j] = fzero;

  load_lds16(Ag,                  &As[0][tid * 8]);
  load_lds16(Ag + (size_t)64 * K, &As[0][tid * 8 + 2048]);
  load_lds16(Bg,                  &Bs[0][tid * 8]);
  load_lds16(Bg + (size_t)64 * K, &Bs[0][tid * 8 + 2048]);

  int buf = 0;
  for (int k0 = 0; k0 < K; k0 += 32) {
    __syncthreads();   // drains own vmcnt -> buf's staging complete for all
    if (k0 + 32 < K) {
      const int nb = buf ^ 1;
      load_lds16(Ag + k0 + 32,                  &As[nb][tid * 8]);
      load_lds16(Ag + (size_t)64 * K + k0 + 32, &As[nb][tid * 8 + 2048]);
      load_lds16(Bg + k0 + 32,                  &Bs[nb][tid * 8]);
      load_lds16(Bg + (size_t)64 * K + k0 + 32, &Bs[nb][tid * 8 + 2048]);
    }
    bf16x8 af[4], bfg[4];
#pragma unroll
    for (int i = 0; i < 4; ++i) af[i]  = *(const bf16x8*)&As[buf][(wr + i * 16 + fr) * 32 + fk];
#pragma unroll
    for (int j = 0; j < 4; ++j) bfg[j] = *(const bf16x8*)&Bs[buf][(wc + j * 16 + fr) * 32 + fk];
#pragma unroll
    for (int i = 0; i < 4; ++i)
#pragma unroll
      for (int j = 0; j < 4; ++j)
        acc[i][j] = MFMA16(af[i], bfg[j], acc[i][j]);
    buf ^= 1;
  }
  const int rbase = (lane >> 4) * 4;
  float* Cb = C + (size_t)(bm * 128 + wr + rbase) * N + bn * 128 + wc + fr;
#pragma unroll
  for (int i = 0; i < 4; ++i)
#pragma unroll
    for (int j = 0; j < 4; ++j)
#pragma unroll
      for (int r = 0; r < 4; ++r)
        Cb[(size_t)(i * 16 + r) * N + j * 16] = acc[i][j][r];
}

// ---------------------------------------------------------------- merged Wq+Wkva GEMM
// R13-verified K-loop over N=2688 (WqT||WkvaT contiguous).
// R18 epilogue fusion (NO trig -- R8's regression was the trig epilogue):
//   bn<16, wc==0 : q nope dims (0..63)  -> (bf16)(v*scale2) pair-packed to qf
//   bn<16, wc==64: q rope dims (64..127)-> f32 q (k_rope_cast consumes)
//   bn in [16,20): kv-latent            -> bf16 pair-packed to kvl (R8-proven code)
//   bn==20       : rope-source cols     -> f32 ckv (k_pack consumes)
// Same FP values as the separate cast kernels (f32 roundtrip is exact) ->
// bit-identical outputs.
__global__ __launch_bounds__(256) void k_gemm_qkva(const __bf16* __restrict__ A,
                                                   const __bf16* __restrict__ Bq,
                                                   float* __restrict__ q,
                                                   float* __restrict__ ckv,
                                                   __bf16* __restrict__ qf,
                                                   __bf16* __restrict__ kvl) {
  const int K = 2048;
  __shared__ __align__(16) __bf16 As[2][128 * 32];
  __shared__ __align__(16) __bf16 Bs[2][128 * 32];
  const int tid  = threadIdx.x;
  const int lane = tid & 63;
  const int wave = tid >> 6;
  const int bm = blockIdx.x, bn = blockIdx.y;
  const int r0 = tid >> 2;
  const int c8 = (tid & 3) * 8;
  const __bf16* Ag = A  + (size_t)(bm * 128 + r0) * K + c8;
  const __bf16* Bg = Bq + (size_t)(bn * 128 + r0) * K + c8;
  const int wr = (wave >> 1) * 64, wc = (wave & 1) * 64;
  const int fr = lane & 15, fk = (lane >> 4) * 8;
  const f32x4 fzero = {0.f, 0.f, 0.f, 0.f};
  f32x4 acc[4][4];
#pragma unroll
  for (int i = 0; i < 4; ++i)
#pragma unroll
    for (int j = 0; j < 4; ++j) acc[i][j] = fzero;

  load_lds16(Ag,                  &As[0][tid * 8]);
  load_lds16(Ag + (size_t)64 * K, &As[0][tid * 8 + 2048]);
  load_lds16(Bg,                  &Bs[0][tid * 8]);
  load_lds16(Bg + (size_t)64 * K, &Bs[0][tid * 8 + 2048]);

  int buf = 0;
  for (int k0 = 0; k0 < K; k0 += 32) {
    __syncthreads();
    if (k0 + 32 < K) {
      const int nb = buf ^ 1;
      load_lds16(Ag + k0 + 32,                  &As[nb][tid * 8]);
      load_lds16(Ag + (size_t)64 * K + k0 + 32, &As[nb][tid * 8 + 2048]);
      load_lds16(Bg + k0 + 32,                  &Bs[nb][tid * 8]);
      load_lds16(Bg + (size_t)64 * K + k0 + 32, &Bs[nb][tid * 8 + 2048]);
    }
    bf16x8 af[4], bfg[4];
#pragma unroll
    for (int i = 0; i < 4; ++i) af[i]  = *(const bf16x8*)&As[buf][(wr + i * 16 + fr) * 32 + fk];
#pragma unroll
    for (int j = 0; j < 4; ++j) bfg[j] = *(const bf16x8*)&Bs[buf][(wc + j * 16 + fr) * 32 + fk];
#pragma unroll
    for (int i = 0; i < 4; ++i)
#pragma unroll
      for (int j = 0; j < 4; ++j)
        acc[i][j] = MFMA16(af[i], bfg[j], acc[i][j]);
    buf ^= 1;
  }
  const int rbase = (lane >> 4) * 4;
  const float scale2 = 1.4426950408889634f / 11.313708498984760f; // log2e/sqrt(128)

  if (bn < 16) {
    const int h = bn;
    if (wc == 0) {
      // nope q dims d = j*16+fr in 0..63: scaled bf16 straight to qf
#pragma unroll
      for (int i = 0; i < 4; ++i) {
#pragma unroll
        for (int j = 0; j < 4; ++j) {
          const int d = j * 16 + fr;
#pragma unroll
          for (int r = 0; r < 4; ++r) {
            const int tg = bm * 128 + wr + rbase + i * 16 + r;
            const int b2 = tg >> 11, tin = tg & 2047;
            float v = acc[i][j][r] * scale2;
            float vo = __shfl_xor(v, 1);
            if ((fr & 1) == 0)
              *(unsigned*)(qf + (((size_t)(b2 * 16 + h) * 2048 + tin) * 128 + d)) =
                  pkbf(v, vo);
          }
        }
      }
    } else {
      // rope q dims (64..127): f32 passthrough; k_rope_cast applies rope
      float* Cb = q + (size_t)(bm * 128 + wr + rbase) * 2048 + h * 128 + 64 + fr;
#pragma unroll
      for (int i = 0; i < 4; ++i)
#pragma unroll
        for (int j = 0; j < 4; ++j)
#pragma unroll
          for (int r = 0; r < 4; ++r)
            Cb[(size_t)(i * 16 + r) * 2048 + j * 16] = acc[i][j][r];
    }
  } else if (bn < 20) {
    // kv-latent columns: bf16 pair-packed straight to kvl
    const int cb = (bn - 16) * 128;
#pragma unroll
    for (int i = 0; i < 4; ++i) {
#pragma unroll
      for (int j = 0; j < 4; ++j) {
        const int c = cb + wc + j * 16 + fr;
#pragma unroll
        for (int r = 0; r < 4; ++r) {
          const int tg = bm * 128 + wr + rbase + i * 16 + r;
          float v = acc[i][j][r];
          float vo = __shfl_xor(v, 1);
          if ((fr & 1) == 0)
            *(unsigned*)(kvl + ((size_t)tg * 512 + c)) = pkbf(v, vo);
        }
      }
    }
  } else {
    // rope-source columns (512..639): f32 ckv for k_pack's rope_kf
    float* Cb = ckv + (size_t)(bm * 128 + wr + rbase) * NKVAP_ + 512 + wc + fr;
#pragma unroll
    for (int i = 0; i < 4; ++i)
#pragma unroll
      for (int j = 0; j < 4; ++j)
#pragma unroll
        for (int r = 0; r < 4; ++r)
          Cb[(size_t)(i * 16 + r) * NKVAP_ + j * 16] = acc[i][j][r];
  }
}

// ---------------------------------------------------------------- rope_q (rope half only)
// R18: nope half + kvl now written by the GEMM epilogue. This kernel ropes
// only d in [64,128): 8 d-elems/thread over B*H*T*8 = 524288 threads = 2048
// blocks. FP ops identical to the previous version's d>=64 branch.
__global__ __launch_bounds__(256) void k_rope_cast(const float* __restrict__ q,
                                                   __bf16* __restrict__ qf) {
  const float scale2 = 1.4426950408889634f / 11.313708498984760f; // log2e/sqrt(128)
  const int idx = blockIdx.x * 256 + threadIdx.x;
  const int d8 = 64 + (idx & 7) * 8;
  const int t  = (idx >> 3) & 2047;
  const int bh = idx >> 14;
  const int h = bh & 15, b = bh >> 4;
  const float* qrow = q + ((size_t)(b * T_ + t)) * 2048 + h * 128 + d8;
  float4 a = *(const float4*)qrow, bb = *(const float4*)(qrow + 4);
  float v[8] = {a.x, a.y, a.z, a.w, bb.x, bb.y, bb.z, bb.w};
  union { __bf16 h8[8]; bf16x8 vv; } o;
#pragma unroll
  for (int p = 0; p < 4; ++p) {
    const int i = ((d8 - 64) >> 1) + p;
    float freq = exp2f(-((float)(2 * i) / 64.0f) * LOG2_THETA);
    float ang = (float)t * freq;
    float c = cosf(ang), s = sinf(ang);
    float x0 = v[2 * p], x1 = v[2 * p + 1];
    o.h8[2 * p]     = (__bf16)((x0 * c - x1 * s) * scale2);
    o.h8[2 * p + 1] = (__bf16)((x0 * s + x1 * c) * scale2);
  }
  *(bf16x8*)(qf + ((size_t)bh * T_ + t) * 128 + d8) = o.vv;
}

// Fragment-packed K layout (consumed by the no-LDS attention kernel):
//   Kp[bh][tile][cg][kg][lane][8 bf16], tile = key>>6, cg = (key>>4)&3,
//   fr = key&15, kg = dim>>5, quad = (dim>>3)&3, e = dim&7, lane = quad*16+fr.
// Vp[bh][tile][g][ks][lane][8]: dim row = g*16+fr, key col = ks*32+quad*8+e.

// ---------------------------------------------------------------- fused pack_kv + rope_kf
// R17-verified. Partition: 1024 (pack_kv) + 2048 (rope_kf) = 3072 blocks.
__global__ __launch_bounds__(256) void k_pack(const float* __restrict__ kv,
                                              const float* __restrict__ ckv,
                                              __bf16* __restrict__ Kp,
                                              __bf16* __restrict__ Vp) {
  __shared__ float tile[64][65];
  const int id = blockIdx.x;
  const int tid = threadIdx.x;
  if (id < 1024) {
    // pack_kv: kv -> Kp nope dims (0..63) AND Vp
    const int bh = id & 31;
    const int t0 = (id >> 5) * 64;
    const int b = bh >> 4, h = bh & 15;
    const int tilei = t0 >> 6;
    const int i0 = tid >> 4, d4 = (tid & 15) * 4;
    const int kg = d4 >> 5, qd = (d4 >> 3) & 3, e = d4 & 7;   // dim coords
#pragma unroll
    for (int p = 0; p < 4; ++p) {
      int i = i0 + p * 16;                                    // key within tile
      const float* src = kv + ((size_t)(b * T_ + t0 + i)) * 1024 + h * 64 + d4;
      float4 v = *(const float4*)src;
      tile[i][d4] = v.x; tile[i][d4 + 1] = v.y; tile[i][d4 + 2] = v.z; tile[i][d4 + 3] = v.w;
      union { __bf16 hh[4]; uint2 u; } o;
      o.hh[0] = (__bf16)v.x; o.hh[1] = (__bf16)v.y; o.hh[2] = (__bf16)v.z; o.hh[3] = (__bf16)v.w;
      const int cg = i >> 4, frk = i & 15;
      size_t koff = (((size_t)(bh * 32 + tilei) * 16) + cg * 4 + kg) * 512
                  + (qd * 16 + frk) * 8 + e;
      *(uint2*)(Kp + koff) = o.u;
    }
    __syncthreads();
    const int dd = tid >> 2, tc0 = (tid & 3) * 16;
    __bf16 outv[16];
#pragma unroll
    for (int j = 0; j < 16; ++j) outv[j] = (__bf16)tile[tc0 + j][dd];
    const int g = dd >> 4, frv = dd & 15;
    const int ks = tc0 >> 5, qv = (tc0 >> 3) & 3;
    size_t voff = (((size_t)(bh * 32 + tilei) * 8) + g * 2 + ks) * 512
                + (qv * 16 + frv) * 8;
    *(bf16x8*)(Vp + voff) = *(bf16x8*)&outv[0];
    *(bf16x8*)(Vp + voff + 128) = *(bf16x8*)&outv[8]; // quad+1 -> +16*8 halfwords
  } else {
    // rope_kf: ckv cols [512,576) -> Kp rope dims, 4 pairs/thread
    const int idx = (id - 1024) * 256 + tid;   // over B*H*T*8 = 524288
    const int i4 = (idx & 7) * 4;              // pair group: i = i4..i4+3
    const int t = (idx >> 3) & 2047;
    const int h = (idx >> 14) & 15;
    const int b = idx >> 18;
    const float* src = ckv + ((size_t)(b * T_ + t)) * NKVAP_ + 512 + 2 * i4;
    float4 a = *(const float4*)src, bb = *(const float4*)(src + 4);
    float v[8] = {a.x, a.y, a.z, a.w, bb.x, bb.y, bb.z, bb.w};
    union { __bf16 h8[8]; bf16x8 vv; } o;
#pragma unroll
    for (int p = 0; p < 4; ++p) {
      const int i = i4 + p;
      float freq = exp2f(-((float)(2 * i) / 64.0f) * LOG2_THETA);
      float ang = (float)t * freq;
      float c = cosf(ang), s = sinf(ang);
      float x0 = v[2 * p], x1 = v[2 * p + 1];
      o.h8[2 * p]     = (__bf16)(x0 * c - x1 * s);
      o.h8[2 * p + 1] = (__bf16)(x0 * s + x1 * c);
    }
    const int bh = b * 16 + h;
    const int tilei = t >> 6, cg = (t >> 4) & 3, frk = t & 15;
    const int kg = 2 + (i4 >> 4), qd = (i4 >> 2) & 3;
    size_t off = (((size_t)(bh * 32 + tilei) * 16) + cg * 4 + kg) * 512
               + (qd * 16 + frk) * 8;
    *(bf16x8*)(Kp + off) = o.vv;
  }
}

// ---------------------------------------------------------------- attention
// R13-verified: load-balanced pairing (each block does qt=p and 31-p), 8
// waves split-K (waves 0-3 even K-tiles, 4-7 odd), fragment-packed K/V
// direct from L2, online-softmax partials merged via 18KB LDS.
__global__ __launch_bounds__(512, 4) void k_attn(const __bf16* __restrict__ qf,
                                                 const __bf16* __restrict__ Kp,
                                                 const __bf16* __restrict__ Vp,
                                                 __bf16* __restrict__ yc) {
  const int blk = blockIdx.x;          // 512 = 16 pair * 32 bh
  const int bh = blk & 31;             // bh mod 8 == XCD -> per-XCD L2 locality
  const int p  = blk >> 5;             // tile pair: qt = p and 31-p
  const int b = bh >> 4, h = bh & 15;
  const int tid = threadIdx.x;
  const int lane = tid & 63, wave = tid >> 6;    // 0..7
  const int w4 = wave & 3, par = wave >> 2;      // q-row group, K-tile parity
  const int fr = lane & 15, quad = lane >> 4, fk8 = quad * 8;

  __shared__ __align__(16) f32x4 mrgO[4][64][4]; // 16 KB partial accO
  __shared__ float mrgML[4][64][2];              // 2 KB partial m,l

  const __bf16* kb = Kp + (size_t)bh * 32 * 8192 + (size_t)lane * 8;
  const __bf16* vb = Vp + (size_t)bh * 32 * 4096 + (size_t)lane * 8;
  const int srcA = (quad & 1) * 32 + fr, srcB = srcA + 16;
  const int hi = quad >> 1;
  const f32x4 fzero = {0.f, 0.f, 0.f, 0.f};

  auto process = [&](int qt) {
    const int qbase = qt * 64;
    const int qi = qbase + w4 * 16 + fr;         // this lane's q-row
    const __bf16* qb = qf + ((size_t)bh * T_ + qi) * HD_;
    bf16x8 aq[4];
#pragma unroll
    for (int g = 0; g < 4; ++g) aq[g] = *(const bf16x8*)(qb + g * 32 + fk8);

    f32x4 accO[4];
#pragma unroll
    for (int g = 0; g < 4; ++g) accO[g] = fzero;
    float m = -1e30f, l = 0.f;

    for (int s0 = par * 64; s0 <= qbase; s0 += 128) {
      const __bf16* kt = kb + (size_t)(s0 >> 6) * 8192;
      const __bf16* vt = vb + (size_t)(s0 >> 6) * 4096;

      // K fragments: 16 coalesced 1KB loads
      bf16x8 kr[4][4];
#pragma unroll
      for (int cg = 0; cg < 4; ++cg)
#pragma unroll
        for (int kg = 0; kg < 4; ++kg)
          kr[cg][kg] = *(const bf16x8*)(kt + (cg * 4 + kg) * 512);

      // S^T: rows = keys (quad*4+r), cols = q (fr)
      f32x4 accST[4];
#pragma unroll
      for (int cg = 0; cg < 4; ++cg) accST[cg] = fzero;
      __builtin_amdgcn_s_setprio(1);
#pragma unroll
      for (int cg = 0; cg < 4; ++cg) {
#pragma unroll
        for (int kg = 0; kg < 4; ++kg)
          accST[cg] = MFMA16(kr[cg][kg], aq[kg], accST[cg]);
      }
      __builtin_amdgcn_s_setprio(0);

      // V fragments issued now; latency hides under the softmax VALU phase
      bf16x8 vr[4][2];
#pragma unroll
      for (int g = 0; g < 4; ++g)
#pragma unroll
        for (int ks = 0; ks < 2; ++ks)
          vr[g][ks] = *(const bf16x8*)(vt + (g * 2 + ks) * 512);

      // row max (mask only on the diagonal tile; values pre-scaled via qf)
      float lmax = -1e30f;
      if (s0 == qbase) {
#pragma unroll
        for (int cg = 0; cg < 4; ++cg) {
#pragma unroll
          for (int r = 0; r < 4; ++r) {
            const int key = s0 + cg * 16 + quad * 4 + r;
            float v = accST[cg][r];
            v = (key <= qi) ? v : -1e30f;
            accST[cg][r] = v;
            lmax = fmaxf(lmax, v);
          }
        }
      } else {
#pragma unroll
        for (int cg = 0; cg < 4; ++cg) {
#pragma unroll
          for (int r = 0; r < 4; ++r) lmax = fmaxf(lmax, accST[cg][r]);
        }
      }
      lmax = fmaxf(lmax, __shfl_xor(lmax, 16, 64));
      lmax = fmaxf(lmax, __shfl_xor(lmax, 32, 64));

      // T13 defer-max: only rescale when the running max grew by > 8
      if (!__all(lmax <= m + 8.0f)) {
        const float mn = fmaxf(m, lmax);
        const float alpha = exp2f(m - mn);
        l *= alpha;
#pragma unroll
        for (int g = 0; g < 4; ++g)
#pragma unroll
          for (int r = 0; r < 4; ++r) accO[g][r] *= alpha;
        m = mn;
      }

      float lsum = 0.f;
      unsigned pk0[4], pk1[4];
#pragma unroll
      for (int cg = 0; cg < 4; ++cg) {
        float p0 = exp2f(accST[cg][0] - m);
        float p1 = exp2f(accST[cg][1] - m);
        float p2 = exp2f(accST[cg][2] - m);
        float p3 = exp2f(accST[cg][3] - m);
        lsum += (p0 + p1) + (p2 + p3);
        pk0[cg] = pkbf(p0, p1);
        pk1[cg] = pkbf(p2, p3);
      }
      lsum += __shfl_xor(lsum, 16, 64);
      lsum += __shfl_xor(lsum, 32, 64);
      l += lsum;

      // PV: B-operand (P) built from register shuffles
#pragma unroll
      for (int ks = 0; ks < 2; ++ks) {
        int a0 = __shfl((int)pk0[2 * ks], srcA, 64);
        int b0 = __shfl((int)pk0[2 * ks + 1], srcA, 64);
        int a1 = __shfl((int)pk1[2 * ks], srcA, 64);
        int b1 = __shfl((int)pk1[2 * ks + 1], srcA, 64);
        int a2 = __shfl((int)pk0[2 * ks], srcB, 64);
        int b2 = __shfl((int)pk0[2 * ks + 1], srcB, 64);
        int a3 = __shfl((int)pk1[2 * ks], srcB, 64);
        int b3 = __shfl((int)pk1[2 * ks + 1], srcB, 64);
        union { int i[4]; bf16x8 v; } pf;
        pf.i[0] = hi ? b0 : a0;
        pf.i[1] = hi ? b1 : a1;
        pf.i[2] = hi ? b2 : a2;
        pf.i[3] = hi ? b3 : a3;
        __builtin_amdgcn_s_setprio(1);
#pragma unroll
        for (int g = 0; g < 4; ++g)
          accO[g] = MFMA16(vr[g][ks], pf.v, accO[g]);
        __builtin_amdgcn_s_setprio(0);
      }
    }

    // split-K merge: odd-parity publish partials, even-parity merge+store
    if (par) {
#pragma unroll
      for (int g = 0; g < 4; ++g) mrgO[w4][lane][g] = accO[g];
      mrgML[w4][lane][0] = m;
      mrgML[w4][lane][1] = l;
    }
    __syncthreads();
    if (!par) {
      const float m1 = mrgML[w4][lane][0];
      const float l1 = mrgML[w4][lane][1];
      const float mn = fmaxf(m, m1);
      const float a0 = exp2f(m - mn), a1 = exp2f(m1 - mn);
      const float lt = l * a0 + l1 * a1;
      const float linv = 1.0f / lt;
      // epilogue: O^T -> yc[(b*T+qi)*1024 + h*64 + d], d = g*16+quad*4+r
      __bf16* yb = yc + ((size_t)(b * T_ + qi)) * 1024 + h * 64 + quad * 4;
#pragma unroll
      for (int g = 0; g < 4; ++g) {
        f32x4 o1 = mrgO[w4][lane][g];
        union { unsigned u[2]; uint2 v; } o;
        o.u[0] = pkbf((accO[g][0] * a0 + o1[0] * a1) * linv,
                      (accO[g][1] * a0 + o1[1] * a1) * linv);
        o.u[1] = pkbf((accO[g][2] * a0 + o1[2] * a1) * linv,
                      (accO[g][3] * a0 + o1[3] * a1) * linv);
        *(uint2*)(yb + g * 16) = o.v;
      }
    }
  };

  process(p);
  __syncthreads();      // protect merge-LDS reuse between the two passes
  process(31 - p);
}

// ---------------------------------------------------------------- launch
extern "C" void kernel_launch(void* const* d_in, const int* in_sizes, int n_in,
                              void* d_out, int out_size, void* d_ws, size_t ws_size,
                              hipStream_t stream) {
  const float* x    = (const float*)d_in[0];
  const float* Wq   = (const float*)d_in[1];
  const float* Wkva = (const float*)d_in[2];
  const float* Wkvb = (const float*)d_in[3];
  const float* Wo   = (const float*)d_in[4];
  float* out = (float*)d_out;
  char* ws = (char*)d_ws;

  // workspace layout (bytes)
  size_t off = 0;
  __bf16* xb    = (__bf16*)(ws + off); off += (size_t)BT_ * C_ * 2;          // 16.78M
  __bf16* WqT   = (__bf16*)(ws + off); off += (size_t)2048 * 2048 * 2;       // 8.39M
  __bf16* WkvaT = (__bf16*)(ws + off); off += (size_t)NKVAP_ * 2048 * 2;     // 2.62M (contiguous after WqT -> combined B, 2688 rows)
  __bf16* WkvbT = (__bf16*)(ws + off); off += (size_t)1024 * 512 * 2;        // 1.05M
  __bf16* WoTc  = (__bf16*)(ws + off); off += (size_t)2048 * 1024 * 2;       // 4.19M
  float*  q     = (float*)(ws + off);  off += (size_t)BT_ * 2048 * 4;        // 33.55M
  float*  ckv   = (float*)(ws + off);  off += (size_t)BT_ * NKVAP_ * 4;      // 10.49M
  __bf16* kvl   = (__bf16*)(ws + off); off += (size_t)BT_ * 512 * 2;         // 4.19M
  float*  kv    = (float*)(ws + off);  off += (size_t)BT_ * 1024 * 4;        // 16.78M
  __bf16* qfb   = (__bf16*)(ws + off); off += (size_t)B_ * H_ * T_ * HD_ * 2;// 16.78M
  __bf16* yc    = (__bf16*)(ws + off); off += (size_t)BT_ * 1024 * 2;        // 8.39M
  // Kp (16.78M) and Vp (8.39M) alias q's 33.55M buffer: q is dead after
  // k_rope_cast, and both are written strictly after it in stream order.
  __bf16* Kp = (__bf16*)q;
  __bf16* Vp = (__bf16*)((char*)q + (size_t)B_ * H_ * T_ * HD_ * 2);

  // 1. fused prologue: cast_x + 4 weight transposes (one dispatch)
  k_prep<<<12032, 256, 0, stream>>>(x, Wq, Wkva, Wkvb, Wo, xb, WqT, WkvaT, WkvbT, WoTc);

  // 2. merged Wq+Wkva projection (N=2688) with fused nope-q/kvl bf16 epilogue
  k_gemm_qkva<<<dim3(BT_ / 128, 2688 / 128), 256, 0, stream>>>(xb, WqT, q, ckv, qfb, kvl);

  // 3. rope for q dims 64..127 only (2048 blocks)
  k_rope_cast<<<2048, 256, 0, stream>>>(q, qfb);

  // 4. kv up-projection, then fused pack_kv + rope_kf (1024 + 2048 blocks)
  k_gemm_bt<<<dim3(BT_ / 128, 1024 / 128), 256, 0, stream>>>(kvl, WkvbT, kv, BT_, 1024, 512);
  k_pack<<<3072, 256, 0, stream>>>(kv, ckv, Kp, Vp);

  // 5. attention (512 blocks x 512 threads; each block does qt=p and 31-p)
  k_attn<<<(T_ / 128) * B_ * H_, 512, 0, stream>>>(qfb, Kp, Vp, yc);

  // 6. output projection
  k_gemm_bt<<<dim3(BT_ / 128, 2048 / 128), 256, 0, stream>>>(yc, WoTc, out, BT_, 2048, 1024);
}

// Round 20
// 288.459 us; speedup vs baseline: 1.0318x; 1.0318x over previous
//
#include <hip/hip_runtime.h>
#include <hip/hip_bf16.h>
#include <math.h>

// Problem constants
#define B_ 2
#define T_ 2048
#define C_ 2048
#define H_ 16
#define HD_ 128
#define LORA_ 512
#define RD_ 64
#define ND_ 64
#define BT_ (B_*T_)            // 4096
#define NKVA_ 576              // LORA + RD
#define NKVAP_ 640             // padded to 128
#define LOG2_THETA 16.609640474436812f

typedef __bf16 bf16x8 __attribute__((ext_vector_type(8)));
typedef float  f32x4  __attribute__((ext_vector_type(4)));

#define MFMA16(a,b,c) __builtin_amdgcn_mfma_f32_16x16x32_bf16((a),(b),(c),0,0,0)

// global -> LDS direct 16B copy (lds dest must be wave-uniform base + lane*16)
__device__ static inline void load_lds16(const __bf16* g, __bf16* l) {
  auto* lp = (__attribute__((address_space(3))) char*)(uintptr_t)(l);
  auto* gp = (const __attribute__((address_space(1))) char*)(g);
  __builtin_amdgcn_global_load_lds(gp, lp, 16, 0, 0);
}

__device__ static inline unsigned pkbf(float a, float b) {
  union { __bf16 h[2]; unsigned u; } v;
  v.h[0] = (__bf16)a; v.h[1] = (__bf16)b;
  return v.u;
}

// ---------------------------------------------------------------- fused prologue
// R14-verified: cast_x + 4 weight transposes, one dispatch.
// Partition: 4096 (cast_x) + 4096 (Wq) + 1280 (Wkva) + 512 (Wkvb) + 2048 (Wo)
__global__ __launch_bounds__(256) void k_prep(const float* __restrict__ x,
                                              const float* __restrict__ Wq,
                                              const float* __restrict__ Wkva,
                                              const float* __restrict__ Wkvb,
                                              const float* __restrict__ Wo,
                                              __bf16* __restrict__ xb,
                                              __bf16* __restrict__ WqT,
                                              __bf16* __restrict__ WkvaT,
                                              __bf16* __restrict__ WkvbT,
                                              __bf16* __restrict__ WoTc) {
  __shared__ float tile[32][33];
  const int id = blockIdx.x;
  const int tid = threadIdx.x;
  if (id < 4096) {
    // cast_x, 8 elems/thread over BT_*C_ = 8388608
    const int idx = id * 256 + tid;
    const float* xp = x + (size_t)idx * 8;
    float4 a = *(const float4*)xp, bb = *(const float4*)(xp + 4);
    union { __bf16 h[8]; bf16x8 v; } o;
    o.h[0] = (__bf16)a.x;  o.h[1] = (__bf16)a.y;
    o.h[2] = (__bf16)a.z;  o.h[3] = (__bf16)a.w;
    o.h[4] = (__bf16)bb.x; o.h[5] = (__bf16)bb.y;
    o.h[6] = (__bf16)bb.z; o.h[7] = (__bf16)bb.w;
    *(bf16x8*)(xb + (size_t)idx * 8) = o.v;
    return;
  }
  const int tx = tid & 31, ty = tid >> 5;
  if (id < 9984) {
    // k_tcast: dst[n][k] = src[k][n], zero-fill n in [N,NP)
    const float* src; __bf16* dst; int K, N, bx, by;
    if (id < 8192)      { src = Wq;   dst = WqT;   K = 2048; N = 2048; int l = id - 4096; bx = l & 63; by = l >> 6; }
    else if (id < 9472) { src = Wkva; dst = WkvaT; K = 2048; N = NKVA_; int l = id - 8192; bx = l & 63; by = l >> 6; }
    else                { src = Wkvb; dst = WkvbT; K = 512;  N = 1024; int l = id - 9472; bx = l & 15; by = l >> 4; }
    const int k0 = bx * 32, n0 = by * 32;
    for (int i = ty; i < 32; i += 8) {
      int n = n0 + tx;
      tile[i][tx] = (n < N) ? src[(size_t)(k0 + i) * N + n] : 0.0f;
    }
    __syncthreads();
    for (int i = ty; i < 32; i += 8)
      dst[(size_t)(n0 + i) * K + k0 + tx] = (__bf16)tile[tx][i];
    return;
  }
  {
    // k_tcast_wo: dst[n][kc] = Wo[(kc>>6)*128 + (kc&63)][n]
    const int l = id - 9984;
    const int kc0 = (l & 31) * 32;
    const int n0  = (l >> 5) * 32;
    const int rbase = (kc0 >> 6) * 128 + (kc0 & 63);
    for (int i = ty; i < 32; i += 8)
      tile[i][tx] = Wo[(size_t)(rbase + i) * C_ + n0 + tx];
    __syncthreads();
    for (int i = ty; i < 32; i += 8)
      WoTc[(size_t)(n0 + i) * 1024 + kc0 + tx] = (__bf16)tile[tx][i];
  }
}

// ---------------------------------------------------------------- GEMM
// R8-verified: 128x128 tile, BK=32, 4 waves, 256 threads, double-buffered
// global_load_lds staging. Used for Wkvb and Wo.
__global__ __launch_bounds__(256) void k_gemm_bt(const __bf16* __restrict__ A,
                                                 const __bf16* __restrict__ B,
                                                 float* __restrict__ C,
                                                 int M, int N, int K) {
  __shared__ __align__(16) __bf16 As[2][128 * 32];
  __shared__ __align__(16) __bf16 Bs[2][128 * 32];
  const int tid  = threadIdx.x;
  const int lane = tid & 63;
  const int wave = tid >> 6;
  const int bm = blockIdx.x, bn = blockIdx.y;
  const int r0 = tid >> 2;
  const int c8 = (tid & 3) * 8;
  const __bf16* Ag = A + (size_t)(bm * 128 + r0) * K + c8;
  const __bf16* Bg = B + (size_t)(bn * 128 + r0) * K + c8;
  const int wr = (wave >> 1) * 64, wc = (wave & 1) * 64;
  const int fr = lane & 15, fk = (lane >> 4) * 8;
  const f32x4 fzero = {0.f, 0.f, 0.f, 0.f};
  f32x4 acc[4][4];
#pragma unroll
  for (int i = 0; i < 4; ++i)
#pragma unroll
    for (int j = 0; j < 4; ++j) acc[i][j] = fzero;

  load_lds16(Ag,                  &As[0][tid * 8]);
  load_lds16(Ag + (size_t)64 * K, &As[0][tid * 8 + 2048]);
  load_lds16(Bg,                  &Bs[0][tid * 8]);
  load_lds16(Bg + (size_t)64 * K, &Bs[0][tid * 8 + 2048]);

  int buf = 0;
  for (int k0 = 0; k0 < K; k0 += 32) {
    __syncthreads();   // drains own vmcnt -> buf's staging complete for all
    if (k0 + 32 < K) {
      const int nb = buf ^ 1;
      load_lds16(Ag + k0 + 32,                  &As[nb][tid * 8]);
      load_lds16(Ag + (size_t)64 * K + k0 + 32, &As[nb][tid * 8 + 2048]);
      load_lds16(Bg + k0 + 32,                  &Bs[nb][tid * 8]);
      load_lds16(Bg + (size_t)64 * K + k0 + 32, &Bs[nb][tid * 8 + 2048]);
    }
    bf16x8 af[4], bfg[4];
#pragma unroll
    for (int i = 0; i < 4; ++i) af[i]  = *(const bf16x8*)&As[buf][(wr + i * 16 + fr) * 32 + fk];
#pragma unroll
    for (int j = 0; j < 4; ++j) bfg[j] = *(const bf16x8*)&Bs[buf][(wc + j * 16 + fr) * 32 + fk];
#pragma unroll
    for (int i = 0; i < 4; ++i)
#pragma unroll
      for (int j = 0; j < 4; ++j)
        acc[i][j] = MFMA16(af[i], bfg[j], acc[i][j]);
    buf ^= 1;
  }
  const int rbase = (lane >> 4) * 4;
  float* Cb = C + (size_t)(bm * 128 + wr + rbase) * N + bn * 128 + wc + fr;
#pragma unroll
  for (int i = 0; i < 4; ++i)
#pragma unroll
    for (int j = 0; j < 4; ++j)
#pragma unroll
      for (int r = 0; r < 4; ++r)
        Cb[(size_t)(i * 16 + r) * N + j * 16] = acc[i][j][r];
}

// ---------------------------------------------------------------- merged Wq+Wkva GEMM
// R13-verified: one dispatch over N=2688 (WqT||WkvaT contiguous), plain f32
// epilogue branching on bn for dest/stride. R18's fused bf16 epilogue
// REGRESSED (+6 us on this latency-bound GEMM: shuffle+predicated stores on
// the critical path at 2.6 blocks/CU) -- keep the plain epilogue.
__global__ __launch_bounds__(256) void k_gemm_qkva(const __bf16* __restrict__ A,
                                                   const __bf16* __restrict__ Bq,
                                                   float* __restrict__ q,
                                                   float* __restrict__ ckv) {
  const int K = 2048;
  __shared__ __align__(16) __bf16 As[2][128 * 32];
  __shared__ __align__(16) __bf16 Bs[2][128 * 32];
  const int tid  = threadIdx.x;
  const int lane = tid & 63;
  const int wave = tid >> 6;
  const int bm = blockIdx.x, bn = blockIdx.y;
  const int r0 = tid >> 2;
  const int c8 = (tid & 3) * 8;
  const __bf16* Ag = A  + (size_t)(bm * 128 + r0) * K + c8;
  const __bf16* Bg = Bq + (size_t)(bn * 128 + r0) * K + c8;
  const int wr = (wave >> 1) * 64, wc = (wave & 1) * 64;
  const int fr = lane & 15, fk = (lane >> 4) * 8;
  const f32x4 fzero = {0.f, 0.f, 0.f, 0.f};
  f32x4 acc[4][4];
#pragma unroll
  for (int i = 0; i < 4; ++i)
#pragma unroll
    for (int j = 0; j < 4; ++j) acc[i][j] = fzero;

  load_lds16(Ag,                  &As[0][tid * 8]);
  load_lds16(Ag + (size_t)64 * K, &As[0][tid * 8 + 2048]);
  load_lds16(Bg,                  &Bs[0][tid * 8]);
  load_lds16(Bg + (size_t)64 * K, &Bs[0][tid * 8 + 2048]);

  int buf = 0;
  for (int k0 = 0; k0 < K; k0 += 32) {
    __syncthreads();
    if (k0 + 32 < K) {
      const int nb = buf ^ 1;
      load_lds16(Ag + k0 + 32,                  &As[nb][tid * 8]);
      load_lds16(Ag + (size_t)64 * K + k0 + 32, &As[nb][tid * 8 + 2048]);
      load_lds16(Bg + k0 + 32,                  &Bs[nb][tid * 8]);
      load_lds16(Bg + (size_t)64 * K + k0 + 32, &Bs[nb][tid * 8 + 2048]);
    }
    bf16x8 af[4], bfg[4];
#pragma unroll
    for (int i = 0; i < 4; ++i) af[i]  = *(const bf16x8*)&As[buf][(wr + i * 16 + fr) * 32 + fk];
#pragma unroll
    for (int j = 0; j < 4; ++j) bfg[j] = *(const bf16x8*)&Bs[buf][(wc + j * 16 + fr) * 32 + fk];
#pragma unroll
    for (int i = 0; i < 4; ++i)
#pragma unroll
      for (int j = 0; j < 4; ++j)
        acc[i][j] = MFMA16(af[i], bfg[j], acc[i][j]);
    buf ^= 1;
  }
  const int rbase = (lane >> 4) * 4;
  float* Cb;
  int stride;
  if (bn < 16) { Cb = q   + (size_t)(bm * 128 + wr + rbase) * 2048 + bn * 128 + wc + fr;        stride = 2048; }
  else         { Cb = ckv + (size_t)(bm * 128 + wr + rbase) * NKVAP_ + (bn - 16) * 128 + wc + fr; stride = NKVAP_; }
#pragma unroll
  for (int i = 0; i < 4; ++i)
#pragma unroll
    for (int j = 0; j < 4; ++j)
#pragma unroll
      for (int r = 0; r < 4; ++r)
        Cb[(size_t)(i * 16 + r) * stride + j * 16] = acc[i][j][r];
}

// ---------------------------------------------------------------- fused rope_q + cast_kvl
// R14/R17-verified: both depend only on the qkva GEMM; one dispatch, both
// vectorized x8. Partition: 4096 (rope_q) + 1024 (cast_kvl) = 5120 blocks.
__global__ __launch_bounds__(256) void k_rope_cast(const float* __restrict__ q,
                                                   const float* __restrict__ ckv,
                                                   __bf16* __restrict__ qf,
                                                   __bf16* __restrict__ kvl) {
  const float scale2 = 1.4426950408889634f / 11.313708498984760f; // log2e/sqrt(128)
  const int id = blockIdx.x;
  const int tid = threadIdx.x;
  if (id < 4096) {
    // rope_q: 8 d-elems/thread over B*H*T*HD/8 = 1048576 threads
    const int idx = id * 256 + tid;
    const int d8 = (idx & 15) * 8;
    const int t  = (idx >> 4) & 2047;
    const int bh = idx >> 15;
    const int h = bh & 15, b = bh >> 4;
    const float* qrow = q + ((size_t)(b * T_ + t)) * 2048 + h * 128 + d8;
    float4 a = *(const float4*)qrow, bb = *(const float4*)(qrow + 4);
    float v[8] = {a.x, a.y, a.z, a.w, bb.x, bb.y, bb.z, bb.w};
    union { __bf16 h8[8]; bf16x8 vv; } o;
    if (d8 < 64) {
#pragma unroll
      for (int j = 0; j < 8; ++j) o.h8[j] = (__bf16)(v[j] * scale2);
    } else {
#pragma unroll
      for (int p = 0; p < 4; ++p) {
        const int i = ((d8 - 64) >> 1) + p;
        float freq = exp2f(-((float)(2 * i) / 64.0f) * LOG2_THETA);
        float ang = (float)t * freq;
        float c = cosf(ang), s = sinf(ang);
        float x0 = v[2 * p], x1 = v[2 * p + 1];
        o.h8[2 * p]     = (__bf16)((x0 * c - x1 * s) * scale2);
        o.h8[2 * p + 1] = (__bf16)((x0 * s + x1 * c) * scale2);
      }
    }
    *(bf16x8*)(qf + ((size_t)bh * T_ + t) * 128 + d8) = o.vv;
  } else {
    // cast_kvl: 8 elems/thread over BT*512/8 = 262144 threads
    const int idx = (id - 4096) * 256 + tid;
    const int r = idx >> 6, c8 = (idx & 63) * 8;
    const float* src = ckv + (size_t)r * NKVAP_ + c8;
    float4 a = *(const float4*)src, bb = *(const float4*)(src + 4);
    union { __bf16 h8[8]; bf16x8 vv; } o;
    o.h8[0] = (__bf16)a.x;  o.h8[1] = (__bf16)a.y;
    o.h8[2] = (__bf16)a.z;  o.h8[3] = (__bf16)a.w;
    o.h8[4] = (__bf16)bb.x; o.h8[5] = (__bf16)bb.y;
    o.h8[6] = (__bf16)bb.z; o.h8[7] = (__bf16)bb.w;
    *(bf16x8*)(kvl + (size_t)r * 512 + c8) = o.vv;
  }
}

// Fragment-packed K layout (consumed by the no-LDS attention kernel):
//   Kp[bh][tile][cg][kg][lane][8 bf16], tile = key>>6, cg = (key>>4)&3,
//   fr = key&15, kg = dim>>5, quad = (dim>>3)&3, e = dim&7, lane = quad*16+fr.
// Vp[bh][tile][g][ks][lane][8]: dim row = g*16+fr, key col = ks*32+quad*8+e.

// ---------------------------------------------------------------- fused pack_kv + rope_kf
// R17-verified. Partition: 1024 (pack_kv) + 2048 (rope_kf) = 3072 blocks.
__global__ __launch_bounds__(256) void k_pack(const float* __restrict__ kv,
                                              const float* __restrict__ ckv,
                                              __bf16* __restrict__ Kp,
                                              __bf16* __restrict__ Vp) {
  __shared__ float tile[64][65];
  const int id = blockIdx.x;
  const int tid = threadIdx.x;
  if (id < 1024) {
    // pack_kv: kv -> Kp nope dims (0..63) AND Vp
    const int bh = id & 31;
    const int t0 = (id >> 5) * 64;
    const int b = bh >> 4, h = bh & 15;
    const int tilei = t0 >> 6;
    const int i0 = tid >> 4, d4 = (tid & 15) * 4;
    const int kg = d4 >> 5, qd = (d4 >> 3) & 3, e = d4 & 7;   // dim coords
#pragma unroll
    for (int p = 0; p < 4; ++p) {
      int i = i0 + p * 16;                                    // key within tile
      const float* src = kv + ((size_t)(b * T_ + t0 + i)) * 1024 + h * 64 + d4;
      float4 v = *(const float4*)src;
      tile[i][d4] = v.x; tile[i][d4 + 1] = v.y; tile[i][d4 + 2] = v.z; tile[i][d4 + 3] = v.w;
      union { __bf16 hh[4]; uint2 u; } o;
      o.hh[0] = (__bf16)v.x; o.hh[1] = (__bf16)v.y; o.hh[2] = (__bf16)v.z; o.hh[3] = (__bf16)v.w;
      const int cg = i >> 4, frk = i & 15;
      size_t koff = (((size_t)(bh * 32 + tilei) * 16) + cg * 4 + kg) * 512
                  + (qd * 16 + frk) * 8 + e;
      *(uint2*)(Kp + koff) = o.u;
    }
    __syncthreads();
    const int dd = tid >> 2, tc0 = (tid & 3) * 16;
    __bf16 outv[16];
#pragma unroll
    for (int j = 0; j < 16; ++j) outv[j] = (__bf16)tile[tc0 + j][dd];
    const int g = dd >> 4, frv = dd & 15;
    const int ks = tc0 >> 5, qv = (tc0 >> 3) & 3;
    size_t voff = (((size_t)(bh * 32 + tilei) * 8) + g * 2 + ks) * 512
                + (qv * 16 + frv) * 8;
    *(bf16x8*)(Vp + voff) = *(bf16x8*)&outv[0];
    *(bf16x8*)(Vp + voff + 128) = *(bf16x8*)&outv[8]; // quad+1 -> +16*8 halfwords
  } else {
    // rope_kf: ckv cols [512,576) -> Kp rope dims, 4 pairs/thread
    const int idx = (id - 1024) * 256 + tid;   // over B*H*T*8 = 524288
    const int i4 = (idx & 7) * 4;              // pair group: i = i4..i4+3
    const int t = (idx >> 3) & 2047;
    const int h = (idx >> 14) & 15;
    const int b = idx >> 18;
    const float* src = ckv + ((size_t)(b * T_ + t)) * NKVAP_ + 512 + 2 * i4;
    float4 a = *(const float4*)src, bb = *(const float4*)(src + 4);
    float v[8] = {a.x, a.y, a.z, a.w, bb.x, bb.y, bb.z, bb.w};
    union { __bf16 h8[8]; bf16x8 vv; } o;
#pragma unroll
    for (int p = 0; p < 4; ++p) {
      const int i = i4 + p;
      float freq = exp2f(-((float)(2 * i) / 64.0f) * LOG2_THETA);
      float ang = (float)t * freq;
      float c = cosf(ang), s = sinf(ang);
      float x0 = v[2 * p], x1 = v[2 * p + 1];
      o.h8[2 * p]     = (__bf16)(x0 * c - x1 * s);
      o.h8[2 * p + 1] = (__bf16)(x0 * s + x1 * c);
    }
    const int bh = b * 16 + h;
    const int tilei = t >> 6, cg = (t >> 4) & 3, frk = t & 15;
    const int kg = 2 + (i4 >> 4), qd = (i4 >> 2) & 3;
    size_t off = (((size_t)(bh * 32 + tilei) * 16) + cg * 4 + kg) * 512
               + (qd * 16 + frk) * 8;
    *(bf16x8*)(Kp + off) = o.vv;
  }
}

// ---------------------------------------------------------------- attention
// R13-verified: load-balanced pairing (each block does qt=p and 31-p), 8
// waves split-K (waves 0-3 even K-tiles, 4-7 odd), fragment-packed K/V
// direct from L2, online-softmax partials merged via 18KB LDS.
__global__ __launch_bounds__(512, 4) void k_attn(const __bf16* __restrict__ qf,
                                                 const __bf16* __restrict__ Kp,
                                                 const __bf16* __restrict__ Vp,
                                                 __bf16* __restrict__ yc) {
  const int blk = blockIdx.x;          // 512 = 16 pair * 32 bh
  const int bh = blk & 31;             // bh mod 8 == XCD -> per-XCD L2 locality
  const int p  = blk >> 5;             // tile pair: qt = p and 31-p
  const int b = bh >> 4, h = bh & 15;
  const int tid = threadIdx.x;
  const int lane = tid & 63, wave = tid >> 6;    // 0..7
  const int w4 = wave & 3, par = wave >> 2;      // q-row group, K-tile parity
  const int fr = lane & 15, quad = lane >> 4, fk8 = quad * 8;

  __shared__ __align__(16) f32x4 mrgO[4][64][4]; // 16 KB partial accO
  __shared__ float mrgML[4][64][2];              // 2 KB partial m,l

  const __bf16* kb = Kp + (size_t)bh * 32 * 8192 + (size_t)lane * 8;
  const __bf16* vb = Vp + (size_t)bh * 32 * 4096 + (size_t)lane * 8;
  const int srcA = (quad & 1) * 32 + fr, srcB = srcA + 16;
  const int hi = quad >> 1;
  const f32x4 fzero = {0.f, 0.f, 0.f, 0.f};

  auto process = [&](int qt) {
    const int qbase = qt * 64;
    const int qi = qbase + w4 * 16 + fr;         // this lane's q-row
    const __bf16* qb = qf + ((size_t)bh * T_ + qi) * HD_;
    bf16x8 aq[4];
#pragma unroll
    for (int g = 0; g < 4; ++g) aq[g] = *(const bf16x8*)(qb + g * 32 + fk8);

    f32x4 accO[4];
#pragma unroll
    for (int g = 0; g < 4; ++g) accO[g] = fzero;
    float m = -1e30f, l = 0.f;

    for (int s0 = par * 64; s0 <= qbase; s0 += 128) {
      const __bf16* kt = kb + (size_t)(s0 >> 6) * 8192;
      const __bf16* vt = vb + (size_t)(s0 >> 6) * 4096;

      // K fragments: 16 coalesced 1KB loads
      bf16x8 kr[4][4];
#pragma unroll
      for (int cg = 0; cg < 4; ++cg)
#pragma unroll
        for (int kg = 0; kg < 4; ++kg)
          kr[cg][kg] = *(const bf16x8*)(kt + (cg * 4 + kg) * 512);

      // S^T: rows = keys (quad*4+r), cols = q (fr)
      f32x4 accST[4];
#pragma unroll
      for (int cg = 0; cg < 4; ++cg) accST[cg] = fzero;
      __builtin_amdgcn_s_setprio(1);
#pragma unroll
      for (int cg = 0; cg < 4; ++cg) {
#pragma unroll
        for (int kg = 0; kg < 4; ++kg)
          accST[cg] = MFMA16(kr[cg][kg], aq[kg], accST[cg]);
      }
      __builtin_amdgcn_s_setprio(0);

      // V fragments issued now; latency hides under the softmax VALU phase
      bf16x8 vr[4][2];
#pragma unroll
      for (int g = 0; g < 4; ++g)
#pragma unroll
        for (int ks = 0; ks < 2; ++ks)
          vr[g][ks] = *(const bf16x8*)(vt + (g * 2 + ks) * 512);

      // row max (mask only on the diagonal tile; values pre-scaled via qf)
      float lmax = -1e30f;
      if (s0 == qbase) {
#pragma unroll
        for (int cg = 0; cg < 4; ++cg) {
#pragma unroll
          for (int r = 0; r < 4; ++r) {
            const int key = s0 + cg * 16 + quad * 4 + r;
            float v = accST[cg][r];
            v = (key <= qi) ? v : -1e30f;
            accST[cg][r] = v;
            lmax = fmaxf(lmax, v);
          }
        }
      } else {
#pragma unroll
        for (int cg = 0; cg < 4; ++cg) {
#pragma unroll
          for (int r = 0; r < 4; ++r) lmax = fmaxf(lmax, accST[cg][r]);
        }
      }
      lmax = fmaxf(lmax, __shfl_xor(lmax, 16, 64));
      lmax = fmaxf(lmax, __shfl_xor(lmax, 32, 64));

      // T13 defer-max: only rescale when the running max grew by > 8
      if (!__all(lmax <= m + 8.0f)) {
        const float mn = fmaxf(m, lmax);
        const float alpha = exp2f(m - mn);
        l *= alpha;
#pragma unroll
        for (int g = 0; g < 4; ++g)
#pragma unroll
          for (int r = 0; r < 4; ++r) accO[g][r] *= alpha;
        m = mn;
      }

      float lsum = 0.f;
      unsigned pk0[4], pk1[4];
#pragma unroll
      for (int cg = 0; cg < 4; ++cg) {
        float p0 = exp2f(accST[cg][0] - m);
        float p1 = exp2f(accST[cg][1] - m);
        float p2 = exp2f(accST[cg][2] - m);
        float p3 = exp2f(accST[cg][3] - m);
        lsum += (p0 + p1) + (p2 + p3);
        pk0[cg] = pkbf(p0, p1);
        pk1[cg] = pkbf(p2, p3);
      }
      lsum += __shfl_xor(lsum, 16, 64);
      lsum += __shfl_xor(lsum, 32, 64);
      l += lsum;

      // PV: B-operand (P) built from register shuffles
#pragma unroll
      for (int ks = 0; ks < 2; ++ks) {
        int a0 = __shfl((int)pk0[2 * ks], srcA, 64);
        int b0 = __shfl((int)pk0[2 * ks + 1], srcA, 64);
        int a1 = __shfl((int)pk1[2 * ks], srcA, 64);
        int b1 = __shfl((int)pk1[2 * ks + 1], srcA, 64);
        int a2 = __shfl((int)pk0[2 * ks], srcB, 64);
        int b2 = __shfl((int)pk0[2 * ks + 1], srcB, 64);
        int a3 = __shfl((int)pk1[2 * ks], srcB, 64);
        int b3 = __shfl((int)pk1[2 * ks + 1], srcB, 64);
        union { int i[4]; bf16x8 v; } pf;
        pf.i[0] = hi ? b0 : a0;
        pf.i[1] = hi ? b1 : a1;
        pf.i[2] = hi ? b2 : a2;
        pf.i[3] = hi ? b3 : a3;
        __builtin_amdgcn_s_setprio(1);
#pragma unroll
        for (int g = 0; g < 4; ++g)
          accO[g] = MFMA16(vr[g][ks], pf.v, accO[g]);
        __builtin_amdgcn_s_setprio(0);
      }
    }

    // split-K merge: odd-parity publish partials, even-parity merge+store
    if (par) {
#pragma unroll
      for (int g = 0; g < 4; ++g) mrgO[w4][lane][g] = accO[g];
      mrgML[w4][lane][0] = m;
      mrgML[w4][lane][1] = l;
    }
    __syncthreads();
    if (!par) {
      const float m1 = mrgML[w4][lane][0];
      const float l1 = mrgML[w4][lane][1];
      const float mn = fmaxf(m, m1);
      const float a0 = exp2f(m - mn), a1 = exp2f(m1 - mn);
      const float lt = l * a0 + l1 * a1;
      const float linv = 1.0f / lt;
      // epilogue: O^T -> yc[(b*T+qi)*1024 + h*64 + d], d = g*16+quad*4+r
      __bf16* yb = yc + ((size_t)(b * T_ + qi)) * 1024 + h * 64 + quad * 4;
#pragma unroll
      for (int g = 0; g < 4; ++g) {
        f32x4 o1 = mrgO[w4][lane][g];
        union { unsigned u[2]; uint2 v; } o;
        o.u[0] = pkbf((accO[g][0] * a0 + o1[0] * a1) * linv,
                      (accO[g][1] * a0 + o1[1] * a1) * linv);
        o.u[1] = pkbf((accO[g][2] * a0 + o1[2] * a1) * linv,
                      (accO[g][3] * a0 + o1[3] * a1) * linv);
        *(uint2*)(yb + g * 16) = o.v;
      }
    }
  };

  process(p);
  __syncthreads();      // protect merge-LDS reuse between the two passes
  process(31 - p);
}

// ---------------------------------------------------------------- launch
extern "C" void kernel_launch(void* const* d_in, const int* in_sizes, int n_in,
                              void* d_out, int out_size, void* d_ws, size_t ws_size,
                              hipStream_t stream) {
  const float* x    = (const float*)d_in[0];
  const float* Wq   = (const float*)d_in[1];
  const float* Wkva = (const float*)d_in[2];
  const float* Wkvb = (const float*)d_in[3];
  const float* Wo   = (const float*)d_in[4];
  float* out = (float*)d_out;
  char* ws = (char*)d_ws;

  // workspace layout (bytes)
  size_t off = 0;
  __bf16* xb    = (__bf16*)(ws + off); off += (size_t)BT_ * C_ * 2;          // 16.78M
  __bf16* WqT   = (__bf16*)(ws + off); off += (size_t)2048 * 2048 * 2;       // 8.39M
  __bf16* WkvaT = (__bf16*)(ws + off); off += (size_t)NKVAP_ * 2048 * 2;     // 2.62M (contiguous after WqT -> combined B, 2688 rows)
  __bf16* WkvbT = (__bf16*)(ws + off); off += (size_t)1024 * 512 * 2;        // 1.05M
  __bf16* WoTc  = (__bf16*)(ws + off); off += (size_t)2048 * 1024 * 2;       // 4.19M
  float*  q     = (float*)(ws + off);  off += (size_t)BT_ * 2048 * 4;        // 33.55M
  float*  ckv   = (float*)(ws + off);  off += (size_t)BT_ * NKVAP_ * 4;      // 10.49M
  __bf16* kvl   = (__bf16*)(ws + off); off += (size_t)BT_ * 512 * 2;         // 4.19M
  float*  kv    = (float*)(ws + off);  off += (size_t)BT_ * 1024 * 4;        // 16.78M
  __bf16* qfb   = (__bf16*)(ws + off); off += (size_t)B_ * H_ * T_ * HD_ * 2;// 16.78M
  __bf16* yc    = (__bf16*)(ws + off); off += (size_t)BT_ * 1024 * 2;        // 8.39M
  // Kp (16.78M) and Vp (8.39M) alias q's 33.55M buffer: q is dead after
  // k_rope_cast, and both are written strictly after it in stream order.
  __bf16* Kp = (__bf16*)q;
  __bf16* Vp = (__bf16*)((char*)q + (size_t)B_ * H_ * T_ * HD_ * 2);

  // 1. fused prologue: cast_x + 4 weight transposes (one dispatch)
  k_prep<<<12032, 256, 0, stream>>>(x, Wq, Wkva, Wkvb, Wo, xb, WqT, WkvaT, WkvbT, WoTc);

  // 2. merged Wq+Wkva projection (N=2688)
  k_gemm_qkva<<<dim3(BT_ / 128, 2688 / 128), 256, 0, stream>>>(xb, WqT, q, ckv);

  // 3. fused rope_q + cast_kvl (vectorized x8)
  k_rope_cast<<<5120, 256, 0, stream>>>(q, ckv, qfb, kvl);

  // 4. kv up-projection, then fused pack_kv + rope_kf (1024 + 2048 blocks)
  k_gemm_bt<<<dim3(BT_ / 128, 1024 / 128), 256, 0, stream>>>(kvl, WkvbT, kv, BT_, 1024, 512);
  k_pack<<<3072, 256, 0, stream>>>(kv, ckv, Kp, Vp);

  // 5. attention (512 blocks x 512 threads; each block does qt=p and 31-p)
  k_attn<<<(T_ / 128) * B_ * H_, 512, 0, stream>>>(qfb, Kp, Vp, yc);

  // 6. output projection
  k_gemm_bt<<<dim3(BT_ / 128, 2048 / 128), 256, 0, stream>>>(yc, WoTc, out, BT_, 2048, 1024);
}

// Round 21
// 285.443 us; speedup vs baseline: 1.0427x; 1.0106x over previous
//
#include <hip/hip_runtime.h>
#include <hip/hip_bf16.h>
#include <math.h>

// Problem constants
#define B_ 2
#define T_ 2048
#define C_ 2048
#define H_ 16
#define HD_ 128
#define LORA_ 512
#define RD_ 64
#define ND_ 64
#define BT_ (B_*T_)            // 4096
#define NKVA_ 576              // LORA + RD
#define NKVAP_ 640             // padded to 128
#define LOG2_THETA 16.609640474436812f

typedef __bf16 bf16x8 __attribute__((ext_vector_type(8)));
typedef float  f32x4  __attribute__((ext_vector_type(4)));

#define MFMA16(a,b,c) __builtin_amdgcn_mfma_f32_16x16x32_bf16((a),(b),(c),0,0,0)

// global -> LDS direct 16B copy (lds dest must be wave-uniform base + lane*16)
__device__ static inline void load_lds16(const __bf16* g, __bf16* l) {
  auto* lp = (__attribute__((address_space(3))) char*)(uintptr_t)(l);
  auto* gp = (const __attribute__((address_space(1))) char*)(g);
  __builtin_amdgcn_global_load_lds(gp, lp, 16, 0, 0);
}

__device__ static inline unsigned pkbf(float a, float b) {
  union { __bf16 h[2]; unsigned u; } v;
  v.h[0] = (__bf16)a; v.h[1] = (__bf16)b;
  return v.u;
}

// ---------------------------------------------------------------- fused prologue
// R14-verified: cast_x + 4 weight transposes, one dispatch.
// Partition: 4096 (cast_x) + 4096 (Wq) + 1280 (Wkva) + 512 (Wkvb) + 2048 (Wo)
__global__ __launch_bounds__(256) void k_prep(const float* __restrict__ x,
                                              const float* __restrict__ Wq,
                                              const float* __restrict__ Wkva,
                                              const float* __restrict__ Wkvb,
                                              const float* __restrict__ Wo,
                                              __bf16* __restrict__ xb,
                                              __bf16* __restrict__ WqT,
                                              __bf16* __restrict__ WkvaT,
                                              __bf16* __restrict__ WkvbT,
                                              __bf16* __restrict__ WoTc) {
  __shared__ float tile[32][33];
  const int id = blockIdx.x;
  const int tid = threadIdx.x;
  if (id < 4096) {
    // cast_x, 8 elems/thread over BT_*C_ = 8388608
    const int idx = id * 256 + tid;
    const float* xp = x + (size_t)idx * 8;
    float4 a = *(const float4*)xp, bb = *(const float4*)(xp + 4);
    union { __bf16 h[8]; bf16x8 v; } o;
    o.h[0] = (__bf16)a.x;  o.h[1] = (__bf16)a.y;
    o.h[2] = (__bf16)a.z;  o.h[3] = (__bf16)a.w;
    o.h[4] = (__bf16)bb.x; o.h[5] = (__bf16)bb.y;
    o.h[6] = (__bf16)bb.z; o.h[7] = (__bf16)bb.w;
    *(bf16x8*)(xb + (size_t)idx * 8) = o.v;
    return;
  }
  const int tx = tid & 31, ty = tid >> 5;
  if (id < 9984) {
    // k_tcast: dst[n][k] = src[k][n], zero-fill n in [N,NP)
    const float* src; __bf16* dst; int K, N, bx, by;
    if (id < 8192)      { src = Wq;   dst = WqT;   K = 2048; N = 2048; int l = id - 4096; bx = l & 63; by = l >> 6; }
    else if (id < 9472) { src = Wkva; dst = WkvaT; K = 2048; N = NKVA_; int l = id - 8192; bx = l & 63; by = l >> 6; }
    else                { src = Wkvb; dst = WkvbT; K = 512;  N = 1024; int l = id - 9472; bx = l & 15; by = l >> 4; }
    const int k0 = bx * 32, n0 = by * 32;
    for (int i = ty; i < 32; i += 8) {
      int n = n0 + tx;
      tile[i][tx] = (n < N) ? src[(size_t)(k0 + i) * N + n] : 0.0f;
    }
    __syncthreads();
    for (int i = ty; i < 32; i += 8)
      dst[(size_t)(n0 + i) * K + k0 + tx] = (__bf16)tile[tx][i];
    return;
  }
  {
    // k_tcast_wo: dst[n][kc] = Wo[(kc>>6)*128 + (kc&63)][n]
    const int l = id - 9984;
    const int kc0 = (l & 31) * 32;
    const int n0  = (l >> 5) * 32;
    const int rbase = (kc0 >> 6) * 128 + (kc0 & 63);
    for (int i = ty; i < 32; i += 8)
      tile[i][tx] = Wo[(size_t)(rbase + i) * C_ + n0 + tx];
    __syncthreads();
    for (int i = ty; i < 32; i += 8)
      WoTc[(size_t)(n0 + i) * 1024 + kc0 + tx] = (__bf16)tile[tx][i];
  }
}

// ---------------------------------------------------------------- GEMM
// R8-verified: 128x128 tile, BK=32, 4 waves, 256 threads, double-buffered
// global_load_lds staging. Used for Wo.
__global__ __launch_bounds__(256) void k_gemm_bt(const __bf16* __restrict__ A,
                                                 const __bf16* __restrict__ B,
                                                 float* __restrict__ C,
                                                 int M, int N, int K) {
  __shared__ __align__(16) __bf16 As[2][128 * 32];
  __shared__ __align__(16) __bf16 Bs[2][128 * 32];
  const int tid  = threadIdx.x;
  const int lane = tid & 63;
  const int wave = tid >> 6;
  const int bm = blockIdx.x, bn = blockIdx.y;
  const int r0 = tid >> 2;
  const int c8 = (tid & 3) * 8;
  const __bf16* Ag = A + (size_t)(bm * 128 + r0) * K + c8;
  const __bf16* Bg = B + (size_t)(bn * 128 + r0) * K + c8;
  const int wr = (wave >> 1) * 64, wc = (wave & 1) * 64;
  const int fr = lane & 15, fk = (lane >> 4) * 8;
  const f32x4 fzero = {0.f, 0.f, 0.f, 0.f};
  f32x4 acc[4][4];
#pragma unroll
  for (int i = 0; i < 4; ++i)
#pragma unroll
    for (int j = 0; j < 4; ++j) acc[i][j] = fzero;

  load_lds16(Ag,                  &As[0][tid * 8]);
  load_lds16(Ag + (size_t)64 * K, &As[0][tid * 8 + 2048]);
  load_lds16(Bg,                  &Bs[0][tid * 8]);
  load_lds16(Bg + (size_t)64 * K, &Bs[0][tid * 8 + 2048]);

  int buf = 0;
  for (int k0 = 0; k0 < K; k0 += 32) {
    __syncthreads();   // drains own vmcnt -> buf's staging complete for all
    if (k0 + 32 < K) {
      const int nb = buf ^ 1;
      load_lds16(Ag + k0 + 32,                  &As[nb][tid * 8]);
      load_lds16(Ag + (size_t)64 * K + k0 + 32, &As[nb][tid * 8 + 2048]);
      load_lds16(Bg + k0 + 32,                  &Bs[nb][tid * 8]);
      load_lds16(Bg + (size_t)64 * K + k0 + 32, &Bs[nb][tid * 8 + 2048]);
    }
    bf16x8 af[4], bfg[4];
#pragma unroll
    for (int i = 0; i < 4; ++i) af[i]  = *(const bf16x8*)&As[buf][(wr + i * 16 + fr) * 32 + fk];
#pragma unroll
    for (int j = 0; j < 4; ++j) bfg[j] = *(const bf16x8*)&Bs[buf][(wc + j * 16 + fr) * 32 + fk];
#pragma unroll
    for (int i = 0; i < 4; ++i)
#pragma unroll
      for (int j = 0; j < 4; ++j)
        acc[i][j] = MFMA16(af[i], bfg[j], acc[i][j]);
    buf ^= 1;
  }
  const int rbase = (lane >> 4) * 4;
  float* Cb = C + (size_t)(bm * 128 + wr + rbase) * N + bn * 128 + wc + fr;
#pragma unroll
  for (int i = 0; i < 4; ++i)
#pragma unroll
    for (int j = 0; j < 4; ++j)
#pragma unroll
      for (int r = 0; r < 4; ++r)
        Cb[(size_t)(i * 16 + r) * N + j * 16] = acc[i][j][r];
}

// ---------------------------------------------------------------- merged Wq+Wkva GEMM
// R13-verified: one dispatch over N=2688 (WqT||WkvaT contiguous), plain f32
// epilogue branching on bn for dest/stride (R18's fused bf16 epilogue
// regressed; keep plain).
__global__ __launch_bounds__(256) void k_gemm_qkva(const __bf16* __restrict__ A,
                                                   const __bf16* __restrict__ Bq,
                                                   float* __restrict__ q,
                                                   float* __restrict__ ckv) {
  const int K = 2048;
  __shared__ __align__(16) __bf16 As[2][128 * 32];
  __shared__ __align__(16) __bf16 Bs[2][128 * 32];
  const int tid  = threadIdx.x;
  const int lane = tid & 63;
  const int wave = tid >> 6;
  const int bm = blockIdx.x, bn = blockIdx.y;
  const int r0 = tid >> 2;
  const int c8 = (tid & 3) * 8;
  const __bf16* Ag = A  + (size_t)(bm * 128 + r0) * K + c8;
  const __bf16* Bg = Bq + (size_t)(bn * 128 + r0) * K + c8;
  const int wr = (wave >> 1) * 64, wc = (wave & 1) * 64;
  const int fr = lane & 15, fk = (lane >> 4) * 8;
  const f32x4 fzero = {0.f, 0.f, 0.f, 0.f};
  f32x4 acc[4][4];
#pragma unroll
  for (int i = 0; i < 4; ++i)
#pragma unroll
    for (int j = 0; j < 4; ++j) acc[i][j] = fzero;

  load_lds16(Ag,                  &As[0][tid * 8]);
  load_lds16(Ag + (size_t)64 * K, &As[0][tid * 8 + 2048]);
  load_lds16(Bg,                  &Bs[0][tid * 8]);
  load_lds16(Bg + (size_t)64 * K, &Bs[0][tid * 8 + 2048]);

  int buf = 0;
  for (int k0 = 0; k0 < K; k0 += 32) {
    __syncthreads();
    if (k0 + 32 < K) {
      const int nb = buf ^ 1;
      load_lds16(Ag + k0 + 32,                  &As[nb][tid * 8]);
      load_lds16(Ag + (size_t)64 * K + k0 + 32, &As[nb][tid * 8 + 2048]);
      load_lds16(Bg + k0 + 32,                  &Bs[nb][tid * 8]);
      load_lds16(Bg + (size_t)64 * K + k0 + 32, &Bs[nb][tid * 8 + 2048]);
    }
    bf16x8 af[4], bfg[4];
#pragma unroll
    for (int i = 0; i < 4; ++i) af[i]  = *(const bf16x8*)&As[buf][(wr + i * 16 + fr) * 32 + fk];
#pragma unroll
    for (int j = 0; j < 4; ++j) bfg[j] = *(const bf16x8*)&Bs[buf][(wc + j * 16 + fr) * 32 + fk];
#pragma unroll
    for (int i = 0; i < 4; ++i)
#pragma unroll
      for (int j = 0; j < 4; ++j)
        acc[i][j] = MFMA16(af[i], bfg[j], acc[i][j]);
    buf ^= 1;
  }
  const int rbase = (lane >> 4) * 4;
  float* Cb;
  int stride;
  if (bn < 16) { Cb = q   + (size_t)(bm * 128 + wr + rbase) * 2048 + bn * 128 + wc + fr;        stride = 2048; }
  else         { Cb = ckv + (size_t)(bm * 128 + wr + rbase) * NKVAP_ + (bn - 16) * 128 + wc + fr; stride = NKVAP_; }
#pragma unroll
  for (int i = 0; i < 4; ++i)
#pragma unroll
    for (int j = 0; j < 4; ++j)
#pragma unroll
      for (int r = 0; r < 4; ++r)
        Cb[(size_t)(i * 16 + r) * stride + j * 16] = acc[i][j][r];
}

// ---------------------------------------------------------------- cast_kvl
// R20: split out of rope_cast -- this is the ONLY true dependency of the kvb
// GEMM. 8 elems/thread over BT*512/8 = 262144 threads = 1024 blocks.
__global__ __launch_bounds__(256) void k_castkvl(const float* __restrict__ ckv,
                                                 __bf16* __restrict__ kvl) {
  const int idx = blockIdx.x * 256 + threadIdx.x;
  const int r = idx >> 6, c8 = (idx & 63) * 8;
  const float* src = ckv + (size_t)r * NKVAP_ + c8;
  float4 a = *(const float4*)src, bb = *(const float4*)(src + 4);
  union { __bf16 h8[8]; bf16x8 vv; } o;
  o.h8[0] = (__bf16)a.x;  o.h8[1] = (__bf16)a.y;
  o.h8[2] = (__bf16)a.z;  o.h8[3] = (__bf16)a.w;
  o.h8[4] = (__bf16)bb.x; o.h8[5] = (__bf16)bb.y;
  o.h8[6] = (__bf16)bb.z; o.h8[7] = (__bf16)bb.w;
  *(bf16x8*)(kvl + (size_t)r * 512 + c8) = o.vv;
}

// ---------------------------------------------------------------- kvb GEMM + rope_q
// R20: the kvb up-projection is only 256 blocks = 1 block/CU (the most
// grid-starved dispatch). rope_q (4096 blocks) is INDEPENDENT of it (reads
// q, writes qf) but was serialized before it. Co-dispatch both: blocks
// 0..255 run the verified GEMM body (M=4096,N=1024,K=512 inlined), blocks
// 256..4351 run the verified rope_q body -- rope blocks fill the CUs the
// GEMM leaves idle. Block-uniform branch; no cross-path dependency.
__global__ __launch_bounds__(256) void k_kvb_rope(const __bf16* __restrict__ A,
                                                  const __bf16* __restrict__ Bw,
                                                  float* __restrict__ C,
                                                  const float* __restrict__ q,
                                                  __bf16* __restrict__ qf) {
  __shared__ __align__(16) __bf16 As[2][128 * 32];
  __shared__ __align__(16) __bf16 Bs[2][128 * 32];
  const int id = blockIdx.x;
  const int tid = threadIdx.x;
  if (id < 256) {
    // kvb GEMM: C[4096][1024] = A[4096][512] * Bw[1024][512]^T, grid 32x8
    const int K = 512, N = 1024;
    const int lane = tid & 63;
    const int wave = tid >> 6;
    const int bm = id & 31, bn = id >> 5;
    const int r0 = tid >> 2;
    const int c8 = (tid & 3) * 8;
    const __bf16* Ag = A  + (size_t)(bm * 128 + r0) * K + c8;
    const __bf16* Bg = Bw + (size_t)(bn * 128 + r0) * K + c8;
    const int wr = (wave >> 1) * 64, wc = (wave & 1) * 64;
    const int fr = lane & 15, fk = (lane >> 4) * 8;
    const f32x4 fzero = {0.f, 0.f, 0.f, 0.f};
    f32x4 acc[4][4];
#pragma unroll
    for (int i = 0; i < 4; ++i)
#pragma unroll
      for (int j = 0; j < 4; ++j) acc[i][j] = fzero;

    load_lds16(Ag,                  &As[0][tid * 8]);
    load_lds16(Ag + (size_t)64 * K, &As[0][tid * 8 + 2048]);
    load_lds16(Bg,                  &Bs[0][tid * 8]);
    load_lds16(Bg + (size_t)64 * K, &Bs[0][tid * 8 + 2048]);

    int buf = 0;
    for (int k0 = 0; k0 < K; k0 += 32) {
      __syncthreads();
      if (k0 + 32 < K) {
        const int nb = buf ^ 1;
        load_lds16(Ag + k0 + 32,                  &As[nb][tid * 8]);
        load_lds16(Ag + (size_t)64 * K + k0 + 32, &As[nb][tid * 8 + 2048]);
        load_lds16(Bg + k0 + 32,                  &Bs[nb][tid * 8]);
        load_lds16(Bg + (size_t)64 * K + k0 + 32, &Bs[nb][tid * 8 + 2048]);
      }
      bf16x8 af[4], bfg[4];
#pragma unroll
      for (int i = 0; i < 4; ++i) af[i]  = *(const bf16x8*)&As[buf][(wr + i * 16 + fr) * 32 + fk];
#pragma unroll
      for (int j = 0; j < 4; ++j) bfg[j] = *(const bf16x8*)&Bs[buf][(wc + j * 16 + fr) * 32 + fk];
#pragma unroll
      for (int i = 0; i < 4; ++i)
#pragma unroll
        for (int j = 0; j < 4; ++j)
          acc[i][j] = MFMA16(af[i], bfg[j], acc[i][j]);
      buf ^= 1;
    }
    const int rbase = (lane >> 4) * 4;
    float* Cb = C + (size_t)(bm * 128 + wr + rbase) * N + bn * 128 + wc + fr;
#pragma unroll
    for (int i = 0; i < 4; ++i)
#pragma unroll
      for (int j = 0; j < 4; ++j)
#pragma unroll
        for (int r = 0; r < 4; ++r)
          Cb[(size_t)(i * 16 + r) * N + j * 16] = acc[i][j][r];
  } else {
    // rope_q: 8 d-elems/thread over B*H*T*HD/8 = 1048576 threads
    const float scale2 = 1.4426950408889634f / 11.313708498984760f; // log2e/sqrt(128)
    const int idx = (id - 256) * 256 + tid;
    const int d8 = (idx & 15) * 8;
    const int t  = (idx >> 4) & 2047;
    const int bh = idx >> 15;
    const int h = bh & 15, b = bh >> 4;
    const float* qrow = q + ((size_t)(b * T_ + t)) * 2048 + h * 128 + d8;
    float4 a = *(const float4*)qrow, bb = *(const float4*)(qrow + 4);
    float v[8] = {a.x, a.y, a.z, a.w, bb.x, bb.y, bb.z, bb.w};
    union { __bf16 h8[8]; bf16x8 vv; } o;
    if (d8 < 64) {
#pragma unroll
      for (int j = 0; j < 8; ++j) o.h8[j] = (__bf16)(v[j] * scale2);
    } else {
#pragma unroll
      for (int p = 0; p < 4; ++p) {
        const int i = ((d8 - 64) >> 1) + p;
        float freq = exp2f(-((float)(2 * i) / 64.0f) * LOG2_THETA);
        float ang = (float)t * freq;
        float c = cosf(ang), s = sinf(ang);
        float x0 = v[2 * p], x1 = v[2 * p + 1];
        o.h8[2 * p]     = (__bf16)((x0 * c - x1 * s) * scale2);
        o.h8[2 * p + 1] = (__bf16)((x0 * s + x1 * c) * scale2);
      }
    }
    *(bf16x8*)(qf + ((size_t)bh * T_ + t) * 128 + d8) = o.vv;
  }
}

// Fragment-packed K layout (consumed by the no-LDS attention kernel):
//   Kp[bh][tile][cg][kg][lane][8 bf16], tile = key>>6, cg = (key>>4)&3,
//   fr = key&15, kg = dim>>5, quad = (dim>>3)&3, e = dim&7, lane = quad*16+fr.
// Vp[bh][tile][g][ks][lane][8]: dim row = g*16+fr, key col = ks*32+quad*8+e.

// ---------------------------------------------------------------- fused pack_kv + rope_kf
// R17-verified. Partition: 1024 (pack_kv) + 2048 (rope_kf) = 3072 blocks.
__global__ __launch_bounds__(256) void k_pack(const float* __restrict__ kv,
                                              const float* __restrict__ ckv,
                                              __bf16* __restrict__ Kp,
                                              __bf16* __restrict__ Vp) {
  __shared__ float tile[64][65];
  const int id = blockIdx.x;
  const int tid = threadIdx.x;
  if (id < 1024) {
    // pack_kv: kv -> Kp nope dims (0..63) AND Vp
    const int bh = id & 31;
    const int t0 = (id >> 5) * 64;
    const int b = bh >> 4, h = bh & 15;
    const int tilei = t0 >> 6;
    const int i0 = tid >> 4, d4 = (tid & 15) * 4;
    const int kg = d4 >> 5, qd = (d4 >> 3) & 3, e = d4 & 7;   // dim coords
#pragma unroll
    for (int p = 0; p < 4; ++p) {
      int i = i0 + p * 16;                                    // key within tile
      const float* src = kv + ((size_t)(b * T_ + t0 + i)) * 1024 + h * 64 + d4;
      float4 v = *(const float4*)src;
      tile[i][d4] = v.x; tile[i][d4 + 1] = v.y; tile[i][d4 + 2] = v.z; tile[i][d4 + 3] = v.w;
      union { __bf16 hh[4]; uint2 u; } o;
      o.hh[0] = (__bf16)v.x; o.hh[1] = (__bf16)v.y; o.hh[2] = (__bf16)v.z; o.hh[3] = (__bf16)v.w;
      const int cg = i >> 4, frk = i & 15;
      size_t koff = (((size_t)(bh * 32 + tilei) * 16) + cg * 4 + kg) * 512
                  + (qd * 16 + frk) * 8 + e;
      *(uint2*)(Kp + koff) = o.u;
    }
    __syncthreads();
    const int dd = tid >> 2, tc0 = (tid & 3) * 16;
    __bf16 outv[16];
#pragma unroll
    for (int j = 0; j < 16; ++j) outv[j] = (__bf16)tile[tc0 + j][dd];
    const int g = dd >> 4, frv = dd & 15;
    const int ks = tc0 >> 5, qv = (tc0 >> 3) & 3;
    size_t voff = (((size_t)(bh * 32 + tilei) * 8) + g * 2 + ks) * 512
                + (qv * 16 + frv) * 8;
    *(bf16x8*)(Vp + voff) = *(bf16x8*)&outv[0];
    *(bf16x8*)(Vp + voff + 128) = *(bf16x8*)&outv[8]; // quad+1 -> +16*8 halfwords
  } else {
    // rope_kf: ckv cols [512,576) -> Kp rope dims, 4 pairs/thread
    const int idx = (id - 1024) * 256 + tid;   // over B*H*T*8 = 524288
    const int i4 = (idx & 7) * 4;              // pair group: i = i4..i4+3
    const int t = (idx >> 3) & 2047;
    const int h = (idx >> 14) & 15;
    const int b = idx >> 18;
    const float* src = ckv + ((size_t)(b * T_ + t)) * NKVAP_ + 512 + 2 * i4;
    float4 a = *(const float4*)src, bb = *(const float4*)(src + 4);
    float v[8] = {a.x, a.y, a.z, a.w, bb.x, bb.y, bb.z, bb.w};
    union { __bf16 h8[8]; bf16x8 vv; } o;
#pragma unroll
    for (int p = 0; p < 4; ++p) {
      const int i = i4 + p;
      float freq = exp2f(-((float)(2 * i) / 64.0f) * LOG2_THETA);
      float ang = (float)t * freq;
      float c = cosf(ang), s = sinf(ang);
      float x0 = v[2 * p], x1 = v[2 * p + 1];
      o.h8[2 * p]     = (__bf16)(x0 * c - x1 * s);
      o.h8[2 * p + 1] = (__bf16)(x0 * s + x1 * c);
    }
    const int bh = b * 16 + h;
    const int tilei = t >> 6, cg = (t >> 4) & 3, frk = t & 15;
    const int kg = 2 + (i4 >> 4), qd = (i4 >> 2) & 3;
    size_t off = (((size_t)(bh * 32 + tilei) * 16) + cg * 4 + kg) * 512
               + (qd * 16 + frk) * 8;
    *(bf16x8*)(Kp + off) = o.vv;
  }
}

// ---------------------------------------------------------------- attention
// R13-verified: load-balanced pairing (each block does qt=p and 31-p), 8
// waves split-K (waves 0-3 even K-tiles, 4-7 odd), fragment-packed K/V
// direct from L2, online-softmax partials merged via 18KB LDS.
__global__ __launch_bounds__(512, 4) void k_attn(const __bf16* __restrict__ qf,
                                                 const __bf16* __restrict__ Kp,
                                                 const __bf16* __restrict__ Vp,
                                                 __bf16* __restrict__ yc) {
  const int blk = blockIdx.x;          // 512 = 16 pair * 32 bh
  const int bh = blk & 31;             // bh mod 8 == XCD -> per-XCD L2 locality
  const int p  = blk >> 5;             // tile pair: qt = p and 31-p
  const int b = bh >> 4, h = bh & 15;
  const int tid = threadIdx.x;
  const int lane = tid & 63, wave = tid >> 6;    // 0..7
  const int w4 = wave & 3, par = wave >> 2;      // q-row group, K-tile parity
  const int fr = lane & 15, quad = lane >> 4, fk8 = quad * 8;

  __shared__ __align__(16) f32x4 mrgO[4][64][4]; // 16 KB partial accO
  __shared__ float mrgML[4][64][2];              // 2 KB partial m,l

  const __bf16* kb = Kp + (size_t)bh * 32 * 8192 + (size_t)lane * 8;
  const __bf16* vb = Vp + (size_t)bh * 32 * 4096 + (size_t)lane * 8;
  const int srcA = (quad & 1) * 32 + fr, srcB = srcA + 16;
  const int hi = quad >> 1;
  const f32x4 fzero = {0.f, 0.f, 0.f, 0.f};

  auto process = [&](int qt) {
    const int qbase = qt * 64;
    const int qi = qbase + w4 * 16 + fr;         // this lane's q-row
    const __bf16* qb = qf + ((size_t)bh * T_ + qi) * HD_;
    bf16x8 aq[4];
#pragma unroll
    for (int g = 0; g < 4; ++g) aq[g] = *(const bf16x8*)(qb + g * 32 + fk8);

    f32x4 accO[4];
#pragma unroll
    for (int g = 0; g < 4; ++g) accO[g] = fzero;
    float m = -1e30f, l = 0.f;

    for (int s0 = par * 64; s0 <= qbase; s0 += 128) {
      const __bf16* kt = kb + (size_t)(s0 >> 6) * 8192;
      const __bf16* vt = vb + (size_t)(s0 >> 6) * 4096;

      // K fragments: 16 coalesced 1KB loads
      bf16x8 kr[4][4];
#pragma unroll
      for (int cg = 0; cg < 4; ++cg)
#pragma unroll
        for (int kg = 0; kg < 4; ++kg)
          kr[cg][kg] = *(const bf16x8*)(kt + (cg * 4 + kg) * 512);

      // S^T: rows = keys (quad*4+r), cols = q (fr)
      f32x4 accST[4];
#pragma unroll
      for (int cg = 0; cg < 4; ++cg) accST[cg] = fzero;
      __builtin_amdgcn_s_setprio(1);
#pragma unroll
      for (int cg = 0; cg < 4; ++cg) {
#pragma unroll
        for (int kg = 0; kg < 4; ++kg)
          accST[cg] = MFMA16(kr[cg][kg], aq[kg], accST[cg]);
      }
      __builtin_amdgcn_s_setprio(0);

      // V fragments issued now; latency hides under the softmax VALU phase
      bf16x8 vr[4][2];
#pragma unroll
      for (int g = 0; g < 4; ++g)
#pragma unroll
        for (int ks = 0; ks < 2; ++ks)
          vr[g][ks] = *(const bf16x8*)(vt + (g * 2 + ks) * 512);

      // row max (mask only on the diagonal tile; values pre-scaled via qf)
      float lmax = -1e30f;
      if (s0 == qbase) {
#pragma unroll
        for (int cg = 0; cg < 4; ++cg) {
#pragma unroll
          for (int r = 0; r < 4; ++r) {
            const int key = s0 + cg * 16 + quad * 4 + r;
            float v = accST[cg][r];
            v = (key <= qi) ? v : -1e30f;
            accST[cg][r] = v;
            lmax = fmaxf(lmax, v);
          }
        }
      } else {
#pragma unroll
        for (int cg = 0; cg < 4; ++cg) {
#pragma unroll
          for (int r = 0; r < 4; ++r) lmax = fmaxf(lmax, accST[cg][r]);
        }
      }
      lmax = fmaxf(lmax, __shfl_xor(lmax, 16, 64));
      lmax = fmaxf(lmax, __shfl_xor(lmax, 32, 64));

      // T13 defer-max: only rescale when the running max grew by > 8
      if (!__all(lmax <= m + 8.0f)) {
        const float mn = fmaxf(m, lmax);
        const float alpha = exp2f(m - mn);
        l *= alpha;
#pragma unroll
        for (int g = 0; g < 4; ++g)
#pragma unroll
          for (int r = 0; r < 4; ++r) accO[g][r] *= alpha;
        m = mn;
      }

      float lsum = 0.f;
      unsigned pk0[4], pk1[4];
#pragma unroll
      for (int cg = 0; cg < 4; ++cg) {
        float p0 = exp2f(accST[cg][0] - m);
        float p1 = exp2f(accST[cg][1] - m);
        float p2 = exp2f(accST[cg][2] - m);
        float p3 = exp2f(accST[cg][3] - m);
        lsum += (p0 + p1) + (p2 + p3);
        pk0[cg] = pkbf(p0, p1);
        pk1[cg] = pkbf(p2, p3);
      }
      lsum += __shfl_xor(lsum, 16, 64);
      lsum += __shfl_xor(lsum, 32, 64);
      l += lsum;

      // PV: B-operand (P) built from register shuffles
#pragma unroll
      for (int ks = 0; ks < 2; ++ks) {
        int a0 = __shfl((int)pk0[2 * ks], srcA, 64);
        int b0 = __shfl((int)pk0[2 * ks + 1], srcA, 64);
        int a1 = __shfl((int)pk1[2 * ks], srcA, 64);
        int b1 = __shfl((int)pk1[2 * ks + 1], srcA, 64);
        int a2 = __shfl((int)pk0[2 * ks], srcB, 64);
        int b2 = __shfl((int)pk0[2 * ks + 1], srcB, 64);
        int a3 = __shfl((int)pk1[2 * ks], srcB, 64);
        int b3 = __shfl((int)pk1[2 * ks + 1], srcB, 64);
        union { int i[4]; bf16x8 v; } pf;
        pf.i[0] = hi ? b0 : a0;
        pf.i[1] = hi ? b1 : a1;
        pf.i[2] = hi ? b2 : a2;
        pf.i[3] = hi ? b3 : a3;
        __builtin_amdgcn_s_setprio(1);
#pragma unroll
        for (int g = 0; g < 4; ++g)
          accO[g] = MFMA16(vr[g][ks], pf.v, accO[g]);
        __builtin_amdgcn_s_setprio(0);
      }
    }

    // split-K merge: odd-parity publish partials, even-parity merge+store
    if (par) {
#pragma unroll
      for (int g = 0; g < 4; ++g) mrgO[w4][lane][g] = accO[g];
      mrgML[w4][lane][0] = m;
      mrgML[w4][lane][1] = l;
    }
    __syncthreads();
    if (!par) {
      const float m1 = mrgML[w4][lane][0];
      const float l1 = mrgML[w4][lane][1];
      const float mn = fmaxf(m, m1);
      const float a0 = exp2f(m - mn), a1 = exp2f(m1 - mn);
      const float lt = l * a0 + l1 * a1;
      const float linv = 1.0f / lt;
      // epilogue: O^T -> yc[(b*T+qi)*1024 + h*64 + d], d = g*16+quad*4+r
      __bf16* yb = yc + ((size_t)(b * T_ + qi)) * 1024 + h * 64 + quad * 4;
#pragma unroll
      for (int g = 0; g < 4; ++g) {
        f32x4 o1 = mrgO[w4][lane][g];
        union { unsigned u[2]; uint2 v; } o;
        o.u[0] = pkbf((accO[g][0] * a0 + o1[0] * a1) * linv,
                      (accO[g][1] * a0 + o1[1] * a1) * linv);
        o.u[1] = pkbf((accO[g][2] * a0 + o1[2] * a1) * linv,
                      (accO[g][3] * a0 + o1[3] * a1) * linv);
        *(uint2*)(yb + g * 16) = o.v;
      }
    }
  };

  process(p);
  __syncthreads();      // protect merge-LDS reuse between the two passes
  process(31 - p);
}

// ---------------------------------------------------------------- launch
extern "C" void kernel_launch(void* const* d_in, const int* in_sizes, int n_in,
                              void* d_out, int out_size, void* d_ws, size_t ws_size,
                              hipStream_t stream) {
  const float* x    = (const float*)d_in[0];
  const float* Wq   = (const float*)d_in[1];
  const float* Wkva = (const float*)d_in[2];
  const float* Wkvb = (const float*)d_in[3];
  const float* Wo   = (const float*)d_in[4];
  float* out = (float*)d_out;
  char* ws = (char*)d_ws;

  // workspace layout (bytes)
  size_t off = 0;
  __bf16* xb    = (__bf16*)(ws + off); off += (size_t)BT_ * C_ * 2;          // 16.78M
  __bf16* WqT   = (__bf16*)(ws + off); off += (size_t)2048 * 2048 * 2;       // 8.39M
  __bf16* WkvaT = (__bf16*)(ws + off); off += (size_t)NKVAP_ * 2048 * 2;     // 2.62M (contiguous after WqT -> combined B, 2688 rows)
  __bf16* WkvbT = (__bf16*)(ws + off); off += (size_t)1024 * 512 * 2;        // 1.05M
  __bf16* WoTc  = (__bf16*)(ws + off); off += (size_t)2048 * 1024 * 2;       // 4.19M
  float*  q     = (float*)(ws + off);  off += (size_t)BT_ * 2048 * 4;        // 33.55M
  float*  ckv   = (float*)(ws + off);  off += (size_t)BT_ * NKVAP_ * 4;      // 10.49M
  __bf16* kvl   = (__bf16*)(ws + off); off += (size_t)BT_ * 512 * 2;        // 4.19M
  float*  kv    = (float*)(ws + off);  off += (size_t)BT_ * 1024 * 4;        // 16.78M
  __bf16* qfb   = (__bf16*)(ws + off); off += (size_t)B_ * H_ * T_ * HD_ * 2;// 16.78M
  __bf16* yc    = (__bf16*)(ws + off); off += (size_t)BT_ * 1024 * 2;        // 8.39M
  // Kp (16.78M) and Vp (8.39M) alias q's 33.55M buffer: q is dead after
  // k_kvb_rope's rope_q, and both are written strictly after it (k_pack).
  __bf16* Kp = (__bf16*)q;
  __bf16* Vp = (__bf16*)((char*)q + (size_t)B_ * H_ * T_ * HD_ * 2);

  // 1. fused prologue: cast_x + 4 weight transposes (one dispatch)
  k_prep<<<12032, 256, 0, stream>>>(x, Wq, Wkva, Wkvb, Wo, xb, WqT, WkvaT, WkvbT, WoTc);

  // 2. merged Wq+Wkva projection (N=2688)
  k_gemm_qkva<<<dim3(BT_ / 128, 2688 / 128), 256, 0, stream>>>(xb, WqT, q, ckv);

  // 3. cast kv-latent (only true dependency of kvb GEMM)
  k_castkvl<<<1024, 256, 0, stream>>>(ckv, kvl);

  // 4. kvb GEMM (256 blocks) co-dispatched with rope_q (4096 blocks)
  k_kvb_rope<<<4352, 256, 0, stream>>>(kvl, WkvbT, kv, q, qfb);

  // 5. fused pack_kv + rope_kf (1024 + 2048 blocks)
  k_pack<<<3072, 256, 0, stream>>>(kv, ckv, Kp, Vp);

  // 6. attention (512 blocks x 512 threads; each block does qt=p and 31-p)
  k_attn<<<(T_ / 128) * B_ * H_, 512, 0, stream>>>(qfb, Kp, Vp, yc);

  // 7. output projection
  k_gemm_bt<<<dim3(BT_ / 128, 2048 / 128), 256, 0, stream>>>(yc, WoTc, out, BT_, 2048, 1024);
}